// Round 12
// baseline (228.911 us; speedup 1.0000x reference)
//
#include <hip/hip_runtime.h>
#include <cstddef>

#define NEDGES   800000
#define NRAD     32
#define MAXZ     100
#define NGRP     (NEDGES / 16)                   // 50000 groups of 16 edges
// ws layout (float units)
#define PT_OFF   0                               // 200*128 u16 = 12800 floats (packed bf16 tables)
#define FB_OFF   12800                           // 4096 u16 = 2048 floats (B-frags, lane order)
#define ZP_OFF   (FB_OFF + 2048)                 // 800000 ints

typedef __attribute__((ext_vector_type(8))) short bf16x8;
typedef __attribute__((ext_vector_type(4))) float f32x4;
typedef __attribute__((ext_vector_type(4))) unsigned int u32x4;

__device__ inline unsigned short f2bf(float f) {            // RTNE f32->bf16
    unsigned u = __float_as_uint(f);
    u += 0x7FFFu + ((u >> 16) & 1u);
    return (unsigned short)(u >> 16);
}
__device__ inline float bflo(unsigned u) { return __uint_as_float(u << 16); }
__device__ inline float bfhi(unsigned u) { return __uint_as_float(u & 0xFFFF0000u); }
__device__ inline float silu(float v) {
    return v * __builtin_amdgcn_rcpf(1.f + __expf(-v));
}

// ---------------------------------------------------------------------------
// Prep (fused): fold weights and emit FINAL bf16 artifacts directly.
//  blocks 0..99  : T1[z][d]=b[d]+embed·We0, T2[z][d]=embed·We1
//                  -> packed PT[z][(d&15)*8 + (d>>4)]          (quarter-read layout)
//  blocks 100..131: Wc[q][d] -> FB[((d>>4)*64 + (q>>3)*16 + (d&15))*8 + (q&7)]
// ---------------------------------------------------------------------------
__global__ __launch_bounds__(128)
void prep_all_kernel(const float* __restrict__ embed_w,
                     const float* __restrict__ w_rbf,
                     const float* __restrict__ w_edge,
                     const float* __restrict__ b_edge,
                     float* __restrict__ ws) {
    const int d = threadIdx.x;
    const int b = blockIdx.x;
    unsigned short* PT = (unsigned short*)(ws + PT_OFF);
    unsigned short* FB = (unsigned short*)(ws + FB_OFF);
    if (b < MAXZ) {
        float a1 = b_edge[d];
        float a2 = 0.f;
        #pragma unroll 8
        for (int k = 0; k < 128; ++k) {
            const float e = embed_w[b * 128 + k];
            a1 = fmaf(e, w_edge[k * 128 + d], a1);
            a2 = fmaf(e, w_edge[(128 + k) * 128 + d], a2);
        }
        const int pc = (d & 15) * 8 + (d >> 4);
        PT[b * 128 + pc]          = f2bf(a1);
        PT[(MAXZ + b) * 128 + pc] = f2bf(a2);
    } else {
        const int q = b - MAXZ;
        float a = 0.f;
        #pragma unroll 8
        for (int m = 0; m < 128; ++m)
            a = fmaf(w_rbf[q * 128 + m], w_edge[(256 + m) * 128 + d], a);
        FB[(((d >> 4) * 64) + ((q >> 3) * 16) + (d & 15)) * 8 + (q & 7)] = f2bf(a);
    }
}

__global__ __launch_bounds__(256)
void zp_kernel(const int* __restrict__ x,
               const int* __restrict__ idx_i,
               const int* __restrict__ idx_j,
               int* __restrict__ zp) {
    const int e = blockIdx.x * 256 + threadIdx.x;
    zp[e] = (x[idx_j[e]] << 8) | x[idx_i[e]];
}

// ---------------------------------------------------------------------------
// Main: one 16-edge group per wave, one-shot (50000 waves).
// OCCUPANCY-FIRST design (the diagnosed binder is waves x memory-MLP):
//   - zero LDS, no pinned bhi array -> __launch_bounds__(256,8) caps VGPR
//     at 64 -> up to 32 waves/CU (was 12). bhi reloaded from FB per MFMA
//     (8KB, L1-hot); tables read from L2 in packed quarter-uniform rows.
//   - compute/epilogue/stores byte-identical to R10 (fastest verified).
// ---------------------------------------------------------------------------
__global__ __launch_bounds__(256, 8)
void edge_kernel(const float* __restrict__ rbf,
                 const int* __restrict__ zp,
                 const float* __restrict__ ws,
                 float* __restrict__ out) {
    const int tid  = threadIdx.x;
    const int lane = tid & 63;
    const int wid  = tid >> 6;
    const int n16  = lane & 15;
    const int kh   = lane >> 4;
    const int grp  = blockIdx.x * 4 + wid;
    const int ebase = grp * 16;

    const unsigned short* __restrict__ PT = (const unsigned short*)(ws + PT_OFF);
    const bf16x8* __restrict__ FB = (const bf16x8*)(ws + FB_OFF);

    // A tile: rbf[ebase+n16][kh*8 .. kh*8+7]
    const f32x4* arow = (const f32x4*)(rbf + (size_t)(ebase + n16) * NRAD + kh * 8);
    const f32x4 a04 = arow[0];
    const f32x4 a44 = arow[1];

    // this quarter's 4 edges' zp (one 64B line per wave)
    const int4 cZ = *(const int4*)(zp + ebase + kh * 4);

    bf16x8 af;
    af[0] = (short)f2bf(a04.x); af[1] = (short)f2bf(a04.y);
    af[2] = (short)f2bf(a04.z); af[3] = (short)f2bf(a04.w);
    af[4] = (short)f2bf(a44.x); af[5] = (short)f2bf(a44.y);
    af[6] = (short)f2bf(a44.z); af[7] = (short)f2bf(a44.w);

    f32x4 acc[8];
    #pragma unroll
    for (int g = 0; g < 8; ++g) {
        const bf16x8 bg = FB[g * 64 + lane];     // L1-hot, reloaded (low VGPR)
        acc[g] = (f32x4){0.f, 0.f, 0.f, 0.f};
        acc[g] = __builtin_amdgcn_mfma_f32_16x16x32_bf16(af, bg, acc[g], 0, 0, 0);
    }

    const int zv[4] = {cZ.x, cZ.y, cZ.z, cZ.w};
    #pragma unroll
    for (int r = 0; r < 4; ++r) {
        const int zj = zv[r] >> 8;
        const int zi = zv[r] & 0xFF;
        // packed rows: 16 lanes x 16B = one 256B row per quarter (L2-hot)
        const u32x4 q1 = *(const u32x4*)(PT + zj * 128 + n16 * 8);
        const u32x4 q2 = *(const u32x4*)(PT + (MAXZ + zi) * 128 + n16 * 8);
        float* __restrict__ op = out + (size_t)(ebase + kh * 4 + r) * 128 + n16;
        #pragma unroll
        for (int k = 0; k < 4; ++k) {
            const float v0 = acc[2 * k][r]     + bflo(q1[k]) + bflo(q2[k]);
            const float v1 = acc[2 * k + 1][r] + bfhi(q1[k]) + bfhi(q2[k]);
            op[16 * (2 * k)]     = silu(v0);
            op[16 * (2 * k + 1)] = silu(v1);
        }
    }
}

extern "C" void kernel_launch(void* const* d_in, const int* in_sizes, int n_in,
                              void* d_out, int out_size, void* d_ws, size_t ws_size,
                              hipStream_t stream) {
    const int*   x       = (const int*)d_in[0];
    const float* rbf     = (const float*)d_in[1];
    const int*   idx_i   = (const int*)d_in[2];
    const int*   idx_j   = (const int*)d_in[3];
    const float* embed_w = (const float*)d_in[4];
    const float* w_rbf   = (const float*)d_in[5];
    const float* w_edge  = (const float*)d_in[6];
    const float* b_edge  = (const float*)d_in[7];
    float* out = (float*)d_out;
    float* ws  = (float*)d_ws;
    int*   zp  = (int*)(ws + ZP_OFF);

    prep_all_kernel<<<MAXZ + NRAD, 128, 0, stream>>>(embed_w, w_rbf, w_edge, b_edge, ws);
    zp_kernel<<<NEDGES / 256, 256, 0, stream>>>(x, idx_i, idx_j, zp);
    edge_kernel<<<NGRP / 4, 256, 0, stream>>>(rbf, zp, ws, out);
}

// Round 13
// 166.432 us; speedup vs baseline: 1.3754x; 1.3754x over previous
//
#include <hip/hip_runtime.h>
#include <cstddef>

#define NEDGES   800000
#define NRAD     32
#define MAXZ     100
#define NGRP     (NEDGES / 16)                   // 50000 groups of 16 edges
#define NBLK     768                             // persistent, 3 blocks/CU
#define WPB      4
#define STRIDE   (NBLK * WPB)                    // 3072 waves
// ws layout (float units)
#define PT_OFF   0                               // 200*128 u16 natural = 12800 floats
#define FB_OFF   12800                           // 4096 u16 = 2048 floats
#define ZP_OFF   (FB_OFF + 2048)                 // 800000 ints
#define TROWD    65                              // LDS table row stride (dwords); 65%32==1

typedef __attribute__((ext_vector_type(8))) short bf16x8;
typedef __attribute__((ext_vector_type(4))) float f32x4;

__device__ inline unsigned short f2bf(float f) {            // RTNE f32->bf16
    unsigned u = __float_as_uint(f);
    u += 0x7FFFu + ((u >> 16) & 1u);
    return (unsigned short)(u >> 16);
}
__device__ inline float bflo(unsigned u) { return __uint_as_float(u << 16); }
__device__ inline float bfhi(unsigned u) { return __uint_as_float(u & 0xFFFF0000u); }
__device__ inline float silu(float v) {
    return v * __builtin_amdgcn_rcpf(1.f + __expf(-v));
}

// ---------------------------------------------------------------------------
// Prep (fused): T1/T2 -> PT natural bf16 [200][128]; Wc -> FB lane-order frags.
// ---------------------------------------------------------------------------
__global__ __launch_bounds__(128)
void prep_all_kernel(const float* __restrict__ embed_w,
                     const float* __restrict__ w_rbf,
                     const float* __restrict__ w_edge,
                     const float* __restrict__ b_edge,
                     float* __restrict__ ws) {
    const int d = threadIdx.x;
    const int b = blockIdx.x;
    unsigned short* PT = (unsigned short*)(ws + PT_OFF);
    unsigned short* FB = (unsigned short*)(ws + FB_OFF);
    if (b < MAXZ) {
        float a1 = b_edge[d];
        float a2 = 0.f;
        #pragma unroll 8
        for (int k = 0; k < 128; ++k) {
            const float e = embed_w[b * 128 + k];
            a1 = fmaf(e, w_edge[k * 128 + d], a1);
            a2 = fmaf(e, w_edge[(128 + k) * 128 + d], a2);
        }
        PT[b * 128 + d]          = f2bf(a1);
        PT[(MAXZ + b) * 128 + d] = f2bf(a2);
    } else {
        const int q = b - MAXZ;
        float a = 0.f;
        #pragma unroll 8
        for (int m = 0; m < 128; ++m)
            a = fmaf(w_rbf[q * 128 + m], w_edge[(256 + m) * 128 + d], a);
        // A-operand frags for transposed mfma: FB[(g*64+lane)*8+j] = Wc[kh*8+j][16g+n16]
        FB[(((d >> 4) * 64) + ((q >> 3) * 16) + (d & 15)) * 8 + (q & 7)] = f2bf(a);
    }
}

__global__ __launch_bounds__(256)
void zp_kernel(const int* __restrict__ x,
               const int* __restrict__ idx_i,
               const int* __restrict__ idx_j,
               int* __restrict__ zp) {
    const int e = blockIdx.x * 256 + threadIdx.x;
    zp[e] = (x[idx_j[e]] << 8) | x[idx_i[e]];
}

// ---------------------------------------------------------------------------
// Main: persistent, LDS bf16 tables (stride 65 dwords -> bank=(z+8g+2kh)%32,
// random-z reads spread across banks), TRANSPOSED MFMA:
//   D[i=out-dim][j=edge] -> lane owns edge n16 x dims {16g8+kh*4..+3}
//   -> stores are 8 x f32x4 per group (4x fewer vmcnt entries than R10's 32
//      scalar stores -- the diagnosed store-ack queue binder)
// Depth-2 A/zp prefetch, wave-private flow, bhi pinned.
// ---------------------------------------------------------------------------
__global__ __launch_bounds__(256, 3)
void edge_kernel(const float* __restrict__ rbf,
                 const int* __restrict__ zp,
                 const float* __restrict__ ws,
                 float* __restrict__ out) {
    __shared__ unsigned int sT[200 * TROWD];     // 52000 B -> 3 blocks/CU

    const int tid = threadIdx.x;
    {   // stage tables: PT natural [200][64 dw] -> sT stride 65 dw
        const unsigned int* __restrict__ src = (const unsigned int*)(ws + PT_OFF);
        for (int i = tid; i < 200 * 64; i += 256) {
            const int z = i >> 6, c = i & 63;
            sT[z * TROWD + c] = src[i];
        }
    }
    __syncthreads();

    const int lane = tid & 63;
    const int wid  = tid >> 6;
    const int n16  = lane & 15;
    const int kh   = lane >> 4;

    const bf16x8* __restrict__ FB = (const bf16x8*)(ws + FB_OFF);
    bf16x8 bhi[8];
    #pragma unroll
    for (int g = 0; g < 8; ++g) {
        bhi[g] = FB[g * 64 + lane];
        asm volatile("" : "+v"(bhi[g]));         // pin: no remat
    }

    auto LOADG = [&](int g, f32x4& a0, f32x4& a4, int& zv) {
        if (g < NGRP) {
            const int eb = g * 16;
            const f32x4* ar = (const f32x4*)(rbf + (size_t)(eb + n16) * NRAD + kh * 8);
            a0 = ar[0]; a4 = ar[1];
            zv = zp[eb + n16];                   // this lane's edge
        }
    };

    auto RUNG = [&](int g, f32x4 c0, f32x4 c4, int zpv) {
        const int ebase = g * 16;
        bf16x8 af;
        af[0] = (short)f2bf(c0.x); af[1] = (short)f2bf(c0.y);
        af[2] = (short)f2bf(c0.z); af[3] = (short)f2bf(c0.w);
        af[4] = (short)f2bf(c4.x); af[5] = (short)f2bf(c4.y);
        af[6] = (short)f2bf(c4.z); af[7] = (short)f2bf(c4.w);

        const int zj = (zpv >> 8) & 0xFF;
        const int zi = zpv & 0xFF;
        const unsigned int* __restrict__ t1 = sT + zj * TROWD;
        const unsigned int* __restrict__ t2 = sT + (MAXZ + zi) * TROWD;
        float* __restrict__ op = out + (size_t)(ebase + n16) * 128 + kh * 4;

        #pragma unroll
        for (int g8 = 0; g8 < 8; ++g8) {
            f32x4 acc = (f32x4){0.f, 0.f, 0.f, 0.f};
            // transposed: A = Wc frag, B = rbf frag
            acc = __builtin_amdgcn_mfma_f32_16x16x32_bf16(bhi[g8], af, acc, 0, 0, 0);
            const int off = 8 * g8 + 2 * kh;     // dword idx of dims 16g8+kh*4..+3
            const uint2 q1 = *(const uint2*)(t1 + off);
            const uint2 q2 = *(const uint2*)(t2 + off);
            f32x4 o;
            o.x = silu(acc[0] + bflo(q1.x) + bflo(q2.x));
            o.y = silu(acc[1] + bfhi(q1.x) + bfhi(q2.x));
            o.z = silu(acc[2] + bflo(q1.y) + bflo(q2.y));
            o.w = silu(acc[3] + bfhi(q1.y) + bfhi(q2.y));
            *(f32x4*)(op + 16 * g8) = o;         // 16B/lane dense store
        }
    };

    int grp = blockIdx.x * WPB + wid;
    f32x4 a0A = {0,0,0,0}, a4A = {0,0,0,0}; int zvA = 0;
    f32x4 a0B = {0,0,0,0}, a4B = {0,0,0,0}; int zvB = 0;
    LOADG(grp,          a0A, a4A, zvA);
    LOADG(grp + STRIDE, a0B, a4B, zvB);

    while (grp < NGRP) {
        {
            const f32x4 c0 = a0A, c4 = a4A; const int cz = zvA;
            LOADG(grp + 2 * STRIDE, a0A, a4A, zvA);
            RUNG(grp, c0, c4, cz);
        }
        grp += STRIDE;
        if (grp >= NGRP) break;
        {
            const f32x4 c0 = a0B, c4 = a4B; const int cz = zvB;
            LOADG(grp + 2 * STRIDE, a0B, a4B, zvB);
            RUNG(grp, c0, c4, cz);
        }
        grp += STRIDE;
    }
}

extern "C" void kernel_launch(void* const* d_in, const int* in_sizes, int n_in,
                              void* d_out, int out_size, void* d_ws, size_t ws_size,
                              hipStream_t stream) {
    const int*   x       = (const int*)d_in[0];
    const float* rbf     = (const float*)d_in[1];
    const int*   idx_i   = (const int*)d_in[2];
    const int*   idx_j   = (const int*)d_in[3];
    const float* embed_w = (const float*)d_in[4];
    const float* w_rbf   = (const float*)d_in[5];
    const float* w_edge  = (const float*)d_in[6];
    const float* b_edge  = (const float*)d_in[7];
    float* out = (float*)d_out;
    float* ws  = (float*)d_ws;
    int*   zp  = (int*)(ws + ZP_OFF);

    prep_all_kernel<<<MAXZ + NRAD, 128, 0, stream>>>(embed_w, w_rbf, w_edge, b_edge, ws);
    zp_kernel<<<NEDGES / 256, 256, 0, stream>>>(x, idx_i, idx_j, zp);
    edge_kernel<<<NBLK, 256, 0, stream>>>(rbf, zp, ws, out);
}